// Round 1
// baseline (535.553 us; speedup 1.0000x reference)
//
#include <hip/hip_runtime.h>

#define NB 32
#define NPTS 1024
#define NP 256
#define NS 16
#define NC 256
#define NH 128
#define NOUT 97

// ---------------------------------------------------------------------------
// Prep: transpose weights so threads (=output channel) read coalesced columns.
// w0ft[c][o] = sa_w0[o][3+c]; w0x[d][o] = sa_w0[o][d]; w*t[c][o] = W[o][c]
// ---------------------------------------------------------------------------
__global__ __launch_bounds__(256) void prep_kernel(
    const float* __restrict__ sa_w0, const float* __restrict__ sa_w1,
    const float* __restrict__ sa_w2, const float* __restrict__ fc_w1,
    const float* __restrict__ fc_w2, const float* __restrict__ fc_w3,
    float* __restrict__ w0ft, float* __restrict__ w0x,
    float* __restrict__ w1t, float* __restrict__ w2t,
    float* __restrict__ fw1t, float* __restrict__ fw2t,
    float* __restrict__ w3t)
{
  int t = blockIdx.x * 256 + threadIdx.x;
  if (t < 256 * 128) { int c = t >> 7, o = t & 127; w0ft[t] = sa_w0[o * 259 + 3 + c]; }
  if (t < 3 * 128)   { int d = t >> 7, o = t & 127; w0x[t]  = sa_w0[o * 259 + d]; }
  if (t < 128 * 128) {
    int c = t >> 7, o = t & 127;
    w1t[t]  = sa_w1[o * 128 + c];
    w2t[t]  = sa_w2[o * 128 + c];
    fw1t[t] = fc_w1[o * 128 + c];
    fw2t[t] = fc_w2[o * 128 + c];
    w3t[t]  = (o < NOUT) ? fc_w3[o * 128 + c] : 0.0f;
  }
}

// ---------------------------------------------------------------------------
// FPS: one block (256 thr) per batch; each thread owns 4 contiguous points in
// registers. Replicates numpy: dist=min(dist,sum((x-c)^2)); argmax first-max.
// fp contract OFF on the distance math so it is bit-identical to the ref.
// ---------------------------------------------------------------------------
__global__ __launch_bounds__(256) void fps_kernel(const float* __restrict__ xyz,
                                                  int* __restrict__ inds)
{
  const int b = blockIdx.x;
  const int t = threadIdx.x;
  const float* xb = xyz + b * NPTS * 3;
  float px[4], py[4], pz[4], dist[4];
#pragma unroll
  for (int j = 0; j < 4; ++j) {
    int n = t * 4 + j;
    px[j] = xb[n * 3 + 0]; py[j] = xb[n * 3 + 1]; pz[j] = xb[n * 3 + 2];
    dist[j] = 1e10f;
  }
  __shared__ float s_val[4];
  __shared__ int   s_idx[4];
  __shared__ int   s_far;
  int far = 0;
  for (int i = 0; i < NP; ++i) {
    if (t == 0) inds[b * NP + i] = far;
    float cx = xb[far * 3 + 0], cy = xb[far * 3 + 1], cz = xb[far * 3 + 2];
    float bv = -1.0f; int bi = 0;
#pragma unroll
    for (int j = 0; j < 4; ++j) {
#pragma clang fp contract(off)
      float dx = px[j] - cx, dy = py[j] - cy, dz = pz[j] - cz;
      float d = (dx * dx + dy * dy) + dz * dz;
      float nd = fminf(dist[j], d);
      dist[j] = nd;
      if (nd > bv) { bv = nd; bi = t * 4 + j; }   // ascending j -> first max
    }
    // wave argmax with first-index tiebreak
    for (int off = 1; off < 64; off <<= 1) {
      float ov = __shfl_xor(bv, off);
      int   oi = __shfl_xor(bi, off);
      if (ov > bv || (ov == bv && oi < bi)) { bv = ov; bi = oi; }
    }
    if ((t & 63) == 0) { s_val[t >> 6] = bv; s_idx[t >> 6] = bi; }
    __syncthreads();
    if (t == 0) {
      float fv = s_val[0]; int fi = s_idx[0];
#pragma unroll
      for (int w = 1; w < 4; ++w)
        if (s_val[w] > fv || (s_val[w] == fv && s_idx[w] < fi)) { fv = s_val[w]; fi = s_idx[w]; }
      s_far = fi;
    }
    __syncthreads();
    far = s_far;
  }
}

// ---------------------------------------------------------------------------
// Ball query: one wave per (b,p). Replicates ref exactly:
// d2 = (|q|^2 + |x|^2) - 2*dot (contract off), threshold (float)0.09,
// first NS in-radius points in index order, remaining slots <- first index.
// ---------------------------------------------------------------------------
__global__ __launch_bounds__(256) void ball_kernel(const float* __restrict__ xyz,
                                                   const int* __restrict__ inds,
                                                   int* __restrict__ nbr)
{
  const int wid  = blockIdx.x * 4 + (threadIdx.x >> 6);   // == b*NP + p
  const int lane = threadIdx.x & 63;
  const int b = wid >> 8;
  const float* xb = xyz + b * NPTS * 3;
  const int ci = inds[wid];
  const float cx = xb[ci * 3 + 0], cy = xb[ci * 3 + 1], cz = xb[ci * 3 + 2];
  float nq;
  {
#pragma clang fp contract(off)
    nq = (cx * cx + cy * cy) + cz * cz;
  }
  const float R2 = 0.09f;   // float(0.3*0.3 in f64) == float(0.09)
  unsigned mask = 0;
  int cnt = 0, firstn = NPTS;
  for (int j = 0; j < 16; ++j) {
#pragma clang fp contract(off)
    int n = lane * 16 + j;   // lane-major: global order == (lane, j) lexicographic
    float x = xb[n * 3 + 0], y = xb[n * 3 + 1], z = xb[n * 3 + 2];
    float nx = (x * x + y * y) + z * z;
    float dt = (cx * x + cy * y) + cz * z;
    float d2 = (nq + nx) - 2.0f * dt;
    if (d2 < R2) { mask |= 1u << j; ++cnt; if (firstn == NPTS) firstn = n; }
  }
  // inclusive prefix sum of counts over lanes
  int inc = cnt;
  for (int off = 1; off < 64; off <<= 1) {
    int v = __shfl_up(inc, off);
    if (lane >= off) inc += v;
  }
  int rank  = inc - cnt;            // exclusive rank of this lane's first hit
  int total = __shfl(inc, 63);
  for (int j = 0; j < 16; ++j) {
    if (mask & (1u << j)) {
      if (rank < NS) nbr[wid * NS + rank] = lane * 16 + j;
      ++rank;
    }
  }
  // overall first in-radius index (min over lanes)
  int fmin = firstn;
  for (int off = 32; off > 0; off >>= 1) {
    int ov = __shfl_xor(fmin, off);
    fmin = min(fmin, ov);
  }
  if (lane < NS && lane >= total) nbr[wid * NS + lane] = fmin;
}

// ---------------------------------------------------------------------------
// G[b][n][o] = sum_c features[b][c][n] * w0ft[c][o]   (layer-0 feature part)
// Block: 128 threads (=o), 16 points. features tile staged in LDS.
// ---------------------------------------------------------------------------
#define GTN 16
__global__ __launch_bounds__(128) void gfeat_kernel(const float* __restrict__ features,
                                                    const float* __restrict__ w0ft,
                                                    float* __restrict__ G)
{
  const int b  = blockIdx.x;
  const int n0 = blockIdx.y * GTN;
  const int o  = threadIdx.x;
  __shared__ __align__(16) float ft[NC][20];   // pad 20 words: 16B-aligned rows
  const float* fb = features + b * NC * NPTS;
#pragma unroll
  for (int r = 0; r < 2; ++r) {
    int c = r * 128 + o;
    const float4* src = reinterpret_cast<const float4*>(fb + c * NPTS + n0);
    float4 v0 = src[0], v1 = src[1], v2 = src[2], v3 = src[3];
    *reinterpret_cast<float4*>(&ft[c][0])  = v0;
    *reinterpret_cast<float4*>(&ft[c][4])  = v1;
    *reinterpret_cast<float4*>(&ft[c][8])  = v2;
    *reinterpret_cast<float4*>(&ft[c][12]) = v3;
  }
  __syncthreads();
  float acc[GTN];
#pragma unroll
  for (int j = 0; j < GTN; ++j) acc[j] = 0.0f;
  for (int c = 0; c < NC; ++c) {
    float w = w0ft[c * 128 + o];
    float4 v0 = *reinterpret_cast<const float4*>(&ft[c][0]);
    float4 v1 = *reinterpret_cast<const float4*>(&ft[c][4]);
    float4 v2 = *reinterpret_cast<const float4*>(&ft[c][8]);
    float4 v3 = *reinterpret_cast<const float4*>(&ft[c][12]);
    acc[0]  += w * v0.x; acc[1]  += w * v0.y; acc[2]  += w * v0.z; acc[3]  += w * v0.w;
    acc[4]  += w * v1.x; acc[5]  += w * v1.y; acc[6]  += w * v1.z; acc[7]  += w * v1.w;
    acc[8]  += w * v2.x; acc[9]  += w * v2.y; acc[10] += w * v2.z; acc[11] += w * v2.w;
    acc[12] += w * v3.x; acc[13] += w * v3.y; acc[14] += w * v3.z; acc[15] += w * v3.w;
  }
#pragma unroll
  for (int j = 0; j < GTN; ++j)
    G[(b * NPTS + n0 + j) * NH + o] = acc[j];
}

// ---------------------------------------------------------------------------
// Main fused kernel: one block (128 thr = output channel) per (b, p).
// L0 (G gather + coord part) -> L1 -> L2 -> maxpool -> FC1 -> FC2 -> FC3.
// LDS x tiles stored [j][o]: writes coalesced, reads are wave-broadcasts.
// ---------------------------------------------------------------------------
__global__ __launch_bounds__(128) void main_kernel(
    const float* __restrict__ xyz, const int* __restrict__ inds,
    const int* __restrict__ nbr, const float* __restrict__ G,
    const float* __restrict__ w0x, const float* __restrict__ s0v, const float* __restrict__ t0v,
    const float* __restrict__ w1t, const float* __restrict__ s1v, const float* __restrict__ t1v,
    const float* __restrict__ w2t, const float* __restrict__ s2v, const float* __restrict__ t2v,
    const float* __restrict__ fw1t, const float* __restrict__ fs1, const float* __restrict__ ft1,
    const float* __restrict__ fw2t, const float* __restrict__ fs2, const float* __restrict__ ft2,
    const float* __restrict__ w3t, const float* __restrict__ b3, float* __restrict__ out)
{
  const int bid = blockIdx.x;           // == b*NP + p
  const int b = bid >> 8;
  const int p = bid & 255;
  const int o = threadIdx.x;
  __shared__ __align__(16) float x1[NS][NH];
  __shared__ __align__(16) float x2[NS][NH];
  __shared__ __align__(16) float fsh[NH];
  __shared__ __align__(16) float hsh[NH];
  __shared__ float gxs[NS][3];
  __shared__ int   idxs[NS];

  if (o < NS) {
    int ci = inds[bid];
    int nj = nbr[bid * NS + o];
    idxs[o] = nj;
    const float* xb = xyz + b * NPTS * 3;
    float cx = xb[ci * 3 + 0], cy = xb[ci * 3 + 1], cz = xb[ci * 3 + 2];
    gxs[o][0] = (xb[nj * 3 + 0] - cx) / 0.3f;
    gxs[o][1] = (xb[nj * 3 + 1] - cy) / 0.3f;
    gxs[o][2] = (xb[nj * 3 + 2] - cz) / 0.3f;
  }
  __syncthreads();

  // L0
  {
    float wa = w0x[o], wb = w0x[NH + o], wc = w0x[2 * NH + o];
    float ss = s0v[o], tt = t0v[o];
#pragma unroll
    for (int j = 0; j < NS; ++j) {
      float g = G[(b * NPTS + idxs[j]) * NH + o];
      float y = g + wa * gxs[j][0] + wb * gxs[j][1] + wc * gxs[j][2];
      x1[j][o] = fmaxf(y * ss + tt, 0.0f);
    }
  }
  __syncthreads();

  // L1
  float acc[NS];
#pragma unroll
  for (int j = 0; j < NS; ++j) acc[j] = 0.0f;
  for (int c4 = 0; c4 < NH / 4; ++c4) {
    int c = c4 * 4;
    float wa = w1t[(c + 0) * NH + o];
    float wb = w1t[(c + 1) * NH + o];
    float wc = w1t[(c + 2) * NH + o];
    float wd = w1t[(c + 3) * NH + o];
#pragma unroll
    for (int j = 0; j < NS; ++j) {
      float4 xv = *reinterpret_cast<const float4*>(&x1[j][c]);
      acc[j] += wa * xv.x + wb * xv.y + wc * xv.z + wd * xv.w;
    }
  }
  {
    float ss = s1v[o], tt = t1v[o];
#pragma unroll
    for (int j = 0; j < NS; ++j) x2[j][o] = fmaxf(acc[j] * ss + tt, 0.0f);
  }
  __syncthreads();

  // L2 + maxpool over neighbors (in-register)
#pragma unroll
  for (int j = 0; j < NS; ++j) acc[j] = 0.0f;
  for (int c4 = 0; c4 < NH / 4; ++c4) {
    int c = c4 * 4;
    float wa = w2t[(c + 0) * NH + o];
    float wb = w2t[(c + 1) * NH + o];
    float wc = w2t[(c + 2) * NH + o];
    float wd = w2t[(c + 3) * NH + o];
#pragma unroll
    for (int j = 0; j < NS; ++j) {
      float4 xv = *reinterpret_cast<const float4*>(&x2[j][c]);
      acc[j] += wa * xv.x + wb * xv.y + wc * xv.z + wd * xv.w;
    }
  }
  {
    float ss = s2v[o], tt = t2v[o];
    float fo = 0.0f;   // relu outputs are >= 0
#pragma unroll
    for (int j = 0; j < NS; ++j) fo = fmaxf(fo, fmaxf(acc[j] * ss + tt, 0.0f));
    fsh[o] = fo;
  }
  __syncthreads();

  // FC1
  {
    float a = 0.0f;
    for (int c4 = 0; c4 < NH / 4; ++c4) {
      int c = c4 * 4;
      float4 fv = *reinterpret_cast<const float4*>(&fsh[c]);
      a += fw1t[(c + 0) * NH + o] * fv.x + fw1t[(c + 1) * NH + o] * fv.y
         + fw1t[(c + 2) * NH + o] * fv.z + fw1t[(c + 3) * NH + o] * fv.w;
    }
    hsh[o] = fmaxf(a * fs1[o] + ft1[o], 0.0f);
  }
  __syncthreads();

  // FC2 (overwrites fsh; all FC1 reads of fsh completed at barrier above)
  {
    float a = 0.0f;
    for (int c4 = 0; c4 < NH / 4; ++c4) {
      int c = c4 * 4;
      float4 hv = *reinterpret_cast<const float4*>(&hsh[c]);
      a += fw2t[(c + 0) * NH + o] * hv.x + fw2t[(c + 1) * NH + o] * hv.y
         + fw2t[(c + 2) * NH + o] * hv.z + fw2t[(c + 3) * NH + o] * hv.w;
    }
    fsh[o] = fmaxf(a * fs2[o] + ft2[o], 0.0f);
  }
  __syncthreads();

  // FC3
  if (o < NOUT) {
    float a = b3[o];
    for (int c4 = 0; c4 < NH / 4; ++c4) {
      int c = c4 * 4;
      float4 hv = *reinterpret_cast<const float4*>(&fsh[c]);
      a += w3t[(c + 0) * NH + o] * hv.x + w3t[(c + 1) * NH + o] * hv.y
         + w3t[(c + 2) * NH + o] * hv.z + w3t[(c + 3) * NH + o] * hv.w;
    }
    out[(b * NOUT + o) * NP + p] = a;
  }
}

extern "C" void kernel_launch(void* const* d_in, const int* in_sizes, int n_in,
                              void* d_out, int out_size, void* d_ws, size_t ws_size,
                              hipStream_t stream) {
  const float* xyz      = (const float*)d_in[0];
  const float* features = (const float*)d_in[1];
  const float* sa_w0 = (const float*)d_in[2];
  const float* sa_s0 = (const float*)d_in[3];
  const float* sa_t0 = (const float*)d_in[4];
  const float* sa_w1 = (const float*)d_in[5];
  const float* sa_s1 = (const float*)d_in[6];
  const float* sa_t1 = (const float*)d_in[7];
  const float* sa_w2 = (const float*)d_in[8];
  const float* sa_s2 = (const float*)d_in[9];
  const float* sa_t2 = (const float*)d_in[10];
  const float* fc_w1 = (const float*)d_in[11];
  const float* fc_s1 = (const float*)d_in[12];
  const float* fc_t1 = (const float*)d_in[13];
  const float* fc_w2 = (const float*)d_in[14];
  const float* fc_s2 = (const float*)d_in[15];
  const float* fc_t2 = (const float*)d_in[16];
  const float* fc_w3 = (const float*)d_in[17];
  const float* fc_b3 = (const float*)d_in[18];
  float* out = (float*)d_out;

  char* ws = (char*)d_ws;
  int* inds = (int*)ws;            ws += (size_t)NB * NP * sizeof(int);
  int* nbr  = (int*)ws;            ws += (size_t)NB * NP * NS * sizeof(int);
  float* w0ft = (float*)ws;        ws += (size_t)256 * 128 * sizeof(float);
  float* w0x  = (float*)ws;        ws += (size_t)3 * 128 * sizeof(float);
  float* w1t  = (float*)ws;        ws += (size_t)128 * 128 * sizeof(float);
  float* w2t  = (float*)ws;        ws += (size_t)128 * 128 * sizeof(float);
  float* fw1t = (float*)ws;        ws += (size_t)128 * 128 * sizeof(float);
  float* fw2t = (float*)ws;        ws += (size_t)128 * 128 * sizeof(float);
  float* w3t  = (float*)ws;        ws += (size_t)128 * 128 * sizeof(float);
  float* G    = (float*)ws;        ws += (size_t)NB * NPTS * NH * sizeof(float);

  prep_kernel<<<128, 256, 0, stream>>>(sa_w0, sa_w1, sa_w2, fc_w1, fc_w2, fc_w3,
                                       w0ft, w0x, w1t, w2t, fw1t, fw2t, w3t);
  fps_kernel<<<NB, 256, 0, stream>>>(xyz, inds);
  ball_kernel<<<NB * NP / 4, 256, 0, stream>>>(xyz, inds, nbr);
  gfeat_kernel<<<dim3(NB, NPTS / GTN), 128, 0, stream>>>(features, w0ft, G);
  main_kernel<<<NB * NP, 128, 0, stream>>>(
      xyz, inds, nbr, G,
      w0x, sa_s0, sa_t0,
      w1t, sa_s1, sa_t1,
      w2t, sa_s2, sa_t2,
      fw1t, fc_s1, fc_t1,
      fw2t, fc_s2, fc_t2,
      w3t, fc_b3, out);
}

// Round 2
// 468.374 us; speedup vs baseline: 1.1434x; 1.1434x over previous
//
#include <hip/hip_runtime.h>

#define NB 32
#define NPTS 1024
#define NP 256
#define NS 16
#define NC 256
#define NH 128
#define NOUT 97
#define GTN 16

// ---------------------------------------------------------------------------
// Prep: transpose weights so threads (=output channel) read coalesced columns.
// w0ft[c][o] = sa_w0[o][3+c]; w0x[d][o] = sa_w0[o][d]; w*t[c][o] = W[o][c]
// ---------------------------------------------------------------------------
__global__ __launch_bounds__(256) void prep_kernel(
    const float* __restrict__ sa_w0, const float* __restrict__ sa_w1,
    const float* __restrict__ sa_w2, const float* __restrict__ fc_w1,
    const float* __restrict__ fc_w2, const float* __restrict__ fc_w3,
    float* __restrict__ w0ft, float* __restrict__ w0x,
    float* __restrict__ w1t, float* __restrict__ w2t,
    float* __restrict__ fw1t, float* __restrict__ fw2t,
    float* __restrict__ w3t)
{
  int t = blockIdx.x * 256 + threadIdx.x;
  if (t < 256 * 128) { int c = t >> 7, o = t & 127; w0ft[t] = sa_w0[o * 259 + 3 + c]; }
  if (t < 3 * 128)   { int d = t >> 7, o = t & 127; w0x[t]  = sa_w0[o * 259 + d]; }
  if (t < 128 * 128) {
    int c = t >> 7, o = t & 127;
    w1t[t]  = sa_w1[o * 128 + c];
    w2t[t]  = sa_w2[o * 128 + c];
    fw1t[t] = fc_w1[o * 128 + c];
    fw2t[t] = fc_w2[o * 128 + c];
    w3t[t]  = (o < NOUT) ? fc_w3[o * 128 + c] : 0.0f;
  }
}

// ---------------------------------------------------------------------------
// Fused FPS + gfeat.
//   blocks [0, NB):      FPS, one 64-lane wave per batch. 16 pts/lane in
//                        registers; xyz mirrored in LDS for centroid lookup.
//                        No __syncthreads on the 256-iteration critical path.
//   blocks [NB, NB+2048): G[b][n][o] = sum_c features[b][c][n] * w0ft[c][o]
// These are independent (gfeat only needs prep's w0ft); fusing lets gfeat
// fill the 224 CUs that FPS leaves idle.
// ---------------------------------------------------------------------------
__global__ __launch_bounds__(128) void fused_fps_gfeat_kernel(
    const float* __restrict__ xyz, int* __restrict__ inds,
    const float* __restrict__ features, const float* __restrict__ w0ft,
    float* __restrict__ G)
{
  __shared__ __align__(16) float smem[NC * 20];   // 20 KB union (fps uses 12 KB)

  if (blockIdx.x < NB) {
    // ------------------------- FPS -------------------------
    if (threadIdx.x >= 64) return;                // single wave
    const int b = blockIdx.x;
    const int lane = threadIdx.x;
    float* s_x = smem;
    float* s_y = smem + NPTS;
    float* s_z = smem + 2 * NPTS;
    const float* xb = xyz + b * NPTS * 3;

    float pts[48];
    const float4* src = reinterpret_cast<const float4*>(xb + lane * 48);
#pragma unroll
    for (int r = 0; r < 12; ++r) {
      float4 v = src[r];
      pts[4 * r + 0] = v.x; pts[4 * r + 1] = v.y;
      pts[4 * r + 2] = v.z; pts[4 * r + 3] = v.w;
    }
    float dist[16];
#pragma unroll
    for (int j = 0; j < 16; ++j) {
      s_x[lane * 16 + j] = pts[3 * j + 0];
      s_y[lane * 16 + j] = pts[3 * j + 1];
      s_z[lane * 16 + j] = pts[3 * j + 2];
      dist[j] = 1e10f;
    }
    // single wave: compiler-inserted lgkmcnt waits order write->read; no barrier
    int far = 0;
    for (int i = 0; i < NP; ++i) {
      if (lane == 0) inds[b * NP + i] = far;
      float cx = s_x[far], cy = s_y[far], cz = s_z[far];   // uniform -> broadcast
      float bv = -1.0f; int bi = 0;
#pragma unroll
      for (int j = 0; j < 16; ++j) {
#pragma clang fp contract(off)
        float dx = pts[3 * j + 0] - cx;
        float dy = pts[3 * j + 1] - cy;
        float dz = pts[3 * j + 2] - cz;
        float d = (dx * dx + dy * dy) + dz * dz;
        float nd = fminf(dist[j], d);
        dist[j] = nd;
        if (nd > bv) { bv = nd; bi = lane * 16 + j; }  // ascending j -> first max
      }
      // wave argmax, first-index tiebreak
#pragma unroll
      for (int off = 1; off < 64; off <<= 1) {
        float ov = __shfl_xor(bv, off);
        int   oi = __shfl_xor(bi, off);
        if (ov > bv || (ov == bv && oi < bi)) { bv = ov; bi = oi; }
      }
      far = bi;
    }
    return;
  }

  // ------------------------- gfeat -------------------------
  const int blk = blockIdx.x - NB;
  const int b  = blk >> 6;
  const int n0 = (blk & 63) * GTN;
  const int o  = threadIdx.x;
  float* ft = smem;                                // [NC][20], pad rows to 20
  const float* fb = features + b * NC * NPTS;
#pragma unroll
  for (int r = 0; r < 2; ++r) {
    int c = r * 128 + o;
    const float4* srcf = reinterpret_cast<const float4*>(fb + c * NPTS + n0);
    float4 v0 = srcf[0], v1 = srcf[1], v2 = srcf[2], v3 = srcf[3];
    *reinterpret_cast<float4*>(&ft[c * 20 + 0])  = v0;
    *reinterpret_cast<float4*>(&ft[c * 20 + 4])  = v1;
    *reinterpret_cast<float4*>(&ft[c * 20 + 8])  = v2;
    *reinterpret_cast<float4*>(&ft[c * 20 + 12]) = v3;
  }
  __syncthreads();
  float acc[GTN];
#pragma unroll
  for (int j = 0; j < GTN; ++j) acc[j] = 0.0f;
  for (int c = 0; c < NC; ++c) {
    float w = w0ft[c * 128 + o];
    float4 v0 = *reinterpret_cast<const float4*>(&ft[c * 20 + 0]);
    float4 v1 = *reinterpret_cast<const float4*>(&ft[c * 20 + 4]);
    float4 v2 = *reinterpret_cast<const float4*>(&ft[c * 20 + 8]);
    float4 v3 = *reinterpret_cast<const float4*>(&ft[c * 20 + 12]);
    acc[0]  += w * v0.x; acc[1]  += w * v0.y; acc[2]  += w * v0.z; acc[3]  += w * v0.w;
    acc[4]  += w * v1.x; acc[5]  += w * v1.y; acc[6]  += w * v1.z; acc[7]  += w * v1.w;
    acc[8]  += w * v2.x; acc[9]  += w * v2.y; acc[10] += w * v2.z; acc[11] += w * v2.w;
    acc[12] += w * v3.x; acc[13] += w * v3.y; acc[14] += w * v3.z; acc[15] += w * v3.w;
  }
#pragma unroll
  for (int j = 0; j < GTN; ++j)
    G[(b * NPTS + n0 + j) * NH + o] = acc[j];
}

// ---------------------------------------------------------------------------
// Ball query: one wave per (b,p). Replicates ref exactly:
// d2 = (|q|^2 + |x|^2) - 2*dot (contract off), threshold (float)0.09,
// first NS in-radius points in index order, remaining slots <- first index.
// ---------------------------------------------------------------------------
__global__ __launch_bounds__(256) void ball_kernel(const float* __restrict__ xyz,
                                                   const int* __restrict__ inds,
                                                   int* __restrict__ nbr)
{
  const int wid  = blockIdx.x * 4 + (threadIdx.x >> 6);   // == b*NP + p
  const int lane = threadIdx.x & 63;
  const int b = wid >> 8;
  const float* xb = xyz + b * NPTS * 3;
  const int ci = inds[wid];
  const float cx = xb[ci * 3 + 0], cy = xb[ci * 3 + 1], cz = xb[ci * 3 + 2];
  float nq;
  {
#pragma clang fp contract(off)
    nq = (cx * cx + cy * cy) + cz * cz;
  }
  const float R2 = 0.09f;
  unsigned mask = 0;
  int cnt = 0, firstn = NPTS;
  for (int j = 0; j < 16; ++j) {
#pragma clang fp contract(off)
    int n = lane * 16 + j;   // lane-major: global order == (lane, j) lexicographic
    float x = xb[n * 3 + 0], y = xb[n * 3 + 1], z = xb[n * 3 + 2];
    float nx = (x * x + y * y) + z * z;
    float dt = (cx * x + cy * y) + cz * z;
    float d2 = (nq + nx) - 2.0f * dt;
    if (d2 < R2) { mask |= 1u << j; ++cnt; if (firstn == NPTS) firstn = n; }
  }
  int inc = cnt;
  for (int off = 1; off < 64; off <<= 1) {
    int v = __shfl_up(inc, off);
    if (lane >= off) inc += v;
  }
  int rank  = inc - cnt;
  int total = __shfl(inc, 63);
  for (int j = 0; j < 16; ++j) {
    if (mask & (1u << j)) {
      if (rank < NS) nbr[wid * NS + rank] = lane * 16 + j;
      ++rank;
    }
  }
  int fmin = firstn;
  for (int off = 32; off > 0; off >>= 1) {
    int ov = __shfl_xor(fmin, off);
    fmin = min(fmin, ov);
  }
  if (lane < NS && lane >= total) nbr[wid * NS + lane] = fmin;
}

// ---------------------------------------------------------------------------
// Main fused kernel: one block (128 thr = output channel) per (b, p).
// L0 (G gather + coord part) -> L1 -> L2 -> maxpool -> FC1 -> FC2 -> FC3.
// ---------------------------------------------------------------------------
__global__ __launch_bounds__(128) void main_kernel(
    const float* __restrict__ xyz, const int* __restrict__ inds,
    const int* __restrict__ nbr, const float* __restrict__ G,
    const float* __restrict__ w0x, const float* __restrict__ s0v, const float* __restrict__ t0v,
    const float* __restrict__ w1t, const float* __restrict__ s1v, const float* __restrict__ t1v,
    const float* __restrict__ w2t, const float* __restrict__ s2v, const float* __restrict__ t2v,
    const float* __restrict__ fw1t, const float* __restrict__ fs1, const float* __restrict__ ft1,
    const float* __restrict__ fw2t, const float* __restrict__ fs2, const float* __restrict__ ft2,
    const float* __restrict__ w3t, const float* __restrict__ b3, float* __restrict__ out)
{
  const int bid = blockIdx.x;           // == b*NP + p
  const int b = bid >> 8;
  const int p = bid & 255;
  const int o = threadIdx.x;
  __shared__ __align__(16) float x1[NS][NH];
  __shared__ __align__(16) float x2[NS][NH];
  __shared__ __align__(16) float fsh[NH];
  __shared__ __align__(16) float hsh[NH];
  __shared__ float gxs[NS][3];
  __shared__ int   idxs[NS];

  if (o < NS) {
    int ci = inds[bid];
    int nj = nbr[bid * NS + o];
    idxs[o] = nj;
    const float* xb = xyz + b * NPTS * 3;
    float cx = xb[ci * 3 + 0], cy = xb[ci * 3 + 1], cz = xb[ci * 3 + 2];
    gxs[o][0] = (xb[nj * 3 + 0] - cx) / 0.3f;
    gxs[o][1] = (xb[nj * 3 + 1] - cy) / 0.3f;
    gxs[o][2] = (xb[nj * 3 + 2] - cz) / 0.3f;
  }
  __syncthreads();

  // L0
  {
    float wa = w0x[o], wb = w0x[NH + o], wc = w0x[2 * NH + o];
    float ss = s0v[o], tt = t0v[o];
#pragma unroll
    for (int j = 0; j < NS; ++j) {
      float g = G[(b * NPTS + idxs[j]) * NH + o];
      float y = g + wa * gxs[j][0] + wb * gxs[j][1] + wc * gxs[j][2];
      x1[j][o] = fmaxf(y * ss + tt, 0.0f);
    }
  }
  __syncthreads();

  // L1
  float acc[NS];
#pragma unroll
  for (int j = 0; j < NS; ++j) acc[j] = 0.0f;
  for (int c4 = 0; c4 < NH / 4; ++c4) {
    int c = c4 * 4;
    float wa = w1t[(c + 0) * NH + o];
    float wb = w1t[(c + 1) * NH + o];
    float wc = w1t[(c + 2) * NH + o];
    float wd = w1t[(c + 3) * NH + o];
#pragma unroll
    for (int j = 0; j < NS; ++j) {
      float4 xv = *reinterpret_cast<const float4*>(&x1[j][c]);
      acc[j] += wa * xv.x + wb * xv.y + wc * xv.z + wd * xv.w;
    }
  }
  {
    float ss = s1v[o], tt = t1v[o];
#pragma unroll
    for (int j = 0; j < NS; ++j) x2[j][o] = fmaxf(acc[j] * ss + tt, 0.0f);
  }
  __syncthreads();

  // L2 + maxpool (in-register)
#pragma unroll
  for (int j = 0; j < NS; ++j) acc[j] = 0.0f;
  for (int c4 = 0; c4 < NH / 4; ++c4) {
    int c = c4 * 4;
    float wa = w2t[(c + 0) * NH + o];
    float wb = w2t[(c + 1) * NH + o];
    float wc = w2t[(c + 2) * NH + o];
    float wd = w2t[(c + 3) * NH + o];
#pragma unroll
    for (int j = 0; j < NS; ++j) {
      float4 xv = *reinterpret_cast<const float4*>(&x2[j][c]);
      acc[j] += wa * xv.x + wb * xv.y + wc * xv.z + wd * xv.w;
    }
  }
  {
    float ss = s2v[o], tt = t2v[o];
    float fo = 0.0f;
#pragma unroll
    for (int j = 0; j < NS; ++j) fo = fmaxf(fo, fmaxf(acc[j] * ss + tt, 0.0f));
    fsh[o] = fo;
  }
  __syncthreads();

  // FC1
  {
    float a = 0.0f;
    for (int c4 = 0; c4 < NH / 4; ++c4) {
      int c = c4 * 4;
      float4 fv = *reinterpret_cast<const float4*>(&fsh[c]);
      a += fw1t[(c + 0) * NH + o] * fv.x + fw1t[(c + 1) * NH + o] * fv.y
         + fw1t[(c + 2) * NH + o] * fv.z + fw1t[(c + 3) * NH + o] * fv.w;
    }
    hsh[o] = fmaxf(a * fs1[o] + ft1[o], 0.0f);
  }
  __syncthreads();

  // FC2
  {
    float a = 0.0f;
    for (int c4 = 0; c4 < NH / 4; ++c4) {
      int c = c4 * 4;
      float4 hv = *reinterpret_cast<const float4*>(&hsh[c]);
      a += fw2t[(c + 0) * NH + o] * hv.x + fw2t[(c + 1) * NH + o] * hv.y
         + fw2t[(c + 2) * NH + o] * hv.z + fw2t[(c + 3) * NH + o] * hv.w;
    }
    fsh[o] = fmaxf(a * fs2[o] + ft2[o], 0.0f);
  }
  __syncthreads();

  // FC3
  if (o < NOUT) {
    float a = b3[o];
    for (int c4 = 0; c4 < NH / 4; ++c4) {
      int c = c4 * 4;
      float4 hv = *reinterpret_cast<const float4*>(&fsh[c]);
      a += w3t[(c + 0) * NH + o] * hv.x + w3t[(c + 1) * NH + o] * hv.y
         + w3t[(c + 2) * NH + o] * hv.z + w3t[(c + 3) * NH + o] * hv.w;
    }
    out[(b * NOUT + o) * NP + p] = a;
  }
}

extern "C" void kernel_launch(void* const* d_in, const int* in_sizes, int n_in,
                              void* d_out, int out_size, void* d_ws, size_t ws_size,
                              hipStream_t stream) {
  const float* xyz      = (const float*)d_in[0];
  const float* features = (const float*)d_in[1];
  const float* sa_w0 = (const float*)d_in[2];
  const float* sa_s0 = (const float*)d_in[3];
  const float* sa_t0 = (const float*)d_in[4];
  const float* sa_w1 = (const float*)d_in[5];
  const float* sa_s1 = (const float*)d_in[6];
  const float* sa_t1 = (const float*)d_in[7];
  const float* sa_w2 = (const float*)d_in[8];
  const float* sa_s2 = (const float*)d_in[9];
  const float* sa_t2 = (const float*)d_in[10];
  const float* fc_w1 = (const float*)d_in[11];
  const float* fc_s1 = (const float*)d_in[12];
  const float* fc_t1 = (const float*)d_in[13];
  const float* fc_w2 = (const float*)d_in[14];
  const float* fc_s2 = (const float*)d_in[15];
  const float* fc_t2 = (const float*)d_in[16];
  const float* fc_w3 = (const float*)d_in[17];
  const float* fc_b3 = (const float*)d_in[18];
  float* out = (float*)d_out;

  char* ws = (char*)d_ws;
  int* inds = (int*)ws;            ws += (size_t)NB * NP * sizeof(int);
  int* nbr  = (int*)ws;            ws += (size_t)NB * NP * NS * sizeof(int);
  float* w0ft = (float*)ws;        ws += (size_t)256 * 128 * sizeof(float);
  float* w0x  = (float*)ws;        ws += (size_t)3 * 128 * sizeof(float);
  float* w1t  = (float*)ws;        ws += (size_t)128 * 128 * sizeof(float);
  float* w2t  = (float*)ws;        ws += (size_t)128 * 128 * sizeof(float);
  float* fw1t = (float*)ws;        ws += (size_t)128 * 128 * sizeof(float);
  float* fw2t = (float*)ws;        ws += (size_t)128 * 128 * sizeof(float);
  float* w3t  = (float*)ws;        ws += (size_t)128 * 128 * sizeof(float);
  float* G    = (float*)ws;        ws += (size_t)NB * NPTS * NH * sizeof(float);

  prep_kernel<<<128, 256, 0, stream>>>(sa_w0, sa_w1, sa_w2, fc_w1, fc_w2, fc_w3,
                                       w0ft, w0x, w1t, w2t, fw1t, fw2t, w3t);
  fused_fps_gfeat_kernel<<<NB + NB * (NPTS / GTN), 128, 0, stream>>>(
      xyz, inds, features, w0ft, G);
  ball_kernel<<<NB * NP / 4, 256, 0, stream>>>(xyz, inds, nbr);
  main_kernel<<<NB * NP, 128, 0, stream>>>(
      xyz, inds, nbr, G,
      w0x, sa_s0, sa_t0,
      w1t, sa_s1, sa_t1,
      w2t, sa_s2, sa_t2,
      fw1t, fc_s1, fc_t1,
      fw2t, fc_s2, fc_t2,
      w3t, fc_b3, out);
}